// Round 15
// baseline (125.393 us; speedup 1.0000x reference)
//
#include <hip/hip_runtime.h>
#include <hip/hip_bf16.h>
#include <math.h>

// Problem constants (B=2, C=256, H=W=64, NUM_HEADS=8, AREA=4)
#define CCH   256
#define NPIX  4096
#define NHD   8
#define HD    32
#define NA    1024
#define BN_EPS 1e-5f
// 1/sqrt(32) * log2(e): folded into Q at qkv_gemm so attn uses raw exp2
#define ATT_SCALE (0.17677669529663687f * 1.4426950408889634f)

typedef __attribute__((ext_vector_type(8))) short bf16x8;
typedef __attribute__((ext_vector_type(4))) short bf16x4;
typedef __attribute__((ext_vector_type(4))) float f32x4;

static __device__ inline short f2bf(float f) {
    union { float f; unsigned u; } v; v.f = f;
    unsigned r = (v.u + 0x7fff + ((v.u >> 16) & 1)) >> 16;  // RNE
    return (short)r;
}

// packed RNE f32x2 -> bf16x2 (low = a, high = b)
static __device__ inline unsigned int pk2bf(float a, float b) {
    __hip_bfloat162 h2 = __float22bfloat162_rn(make_float2(a, b));
    union { __hip_bfloat162 h; unsigned int u; } v; v.h = h2;
    return v.u;
}

// ---------------------------------------------------------------------------
// Kernel: fused input prep (proven, untouched).
//  z = 0,1 : transpose+cast x[b][c][n] f32 -> Xt[b*4096+n][c] bf16 (b = z).
//  z = 2   : cast all weights to bf16 into Wb.
// grid (64, 4, 3), block 256.
// ---------------------------------------------------------------------------
__global__ __launch_bounds__(256)
void prep_kernel(const float* __restrict__ x, short* __restrict__ Xt,
                 const float* __restrict__ wqk, const float* __restrict__ wv,
                 const float* __restrict__ wp, short* __restrict__ Wb) {
    __shared__ short tile[64][66];
    const int t = threadIdx.x;
    const int z = blockIdx.z;
    if (z == 2) {
        const int id  = blockIdx.y * 64 + blockIdx.x;        // 0..255
        const int idx = (id * 256 + t) * 4;
        const float* src; int off;
        if (idx < 131072)      { src = wqk; off = idx; }
        else if (idx < 196608) { src = wv;  off = idx - 131072; }
        else                   { src = wp;  off = idx - 196608; }
        const float4 v = *(const float4*)(src + off);
        short4 o;
        o.x = f2bf(v.x); o.y = f2bf(v.y); o.z = f2bf(v.z); o.w = f2bf(v.w);
        *(short4*)(Wb + idx) = o;
        return;
    }
    const int n0 = blockIdx.x << 6;
    const int c0 = blockIdx.y << 6;
    const int b  = z;
    const float* xp = x + (((size_t)(b * CCH + c0)) << 12) + n0;
    #pragma unroll
    for (int j = 0; j < 16; ++j) {
        const int lin = (j << 8) + t;
        const int cl = lin >> 6, nl = lin & 63;
        tile[cl][nl] = f2bf(xp[((size_t)cl << 12) + nl]);
    }
    __syncthreads();
    short* xtp = Xt + ((((size_t)b << 12) + n0) << 8) + c0;
    #pragma unroll
    for (int j = 0; j < 16; ++j) {
        const int lin = (j << 8) + t;
        const int nl = lin >> 6, cl = lin & 63;
        xtp[((size_t)nl << 8) + cl] = tile[cl][nl];
    }
}

// ---------------------------------------------------------------------------
// Kernel: fused QKV GEMM, LDS-staged, 128x64 block tile (R14 proven, untouched).
// D[i][o] = sum_c Xt[i][c] * Wb[o][c], i=0..8191, o=0..767.
// Block tile 128m x 64n x BK=64; 4 waves (2m x 2n), wave tile 64x32.
// grid (64, 12) = 768 blocks, 3 blocks/CU.
// ---------------------------------------------------------------------------
__global__ __launch_bounds__(256)
void qkv_gemm(const short* __restrict__ Xt, const short* __restrict__ Wb,
              const float* __restrict__ g_qk, const float* __restrict__ b_qk,
              const float* __restrict__ m_qk, const float* __restrict__ v_qk,
              const float* __restrict__ g_v, const float* __restrict__ b_v,
              const float* __restrict__ m_v, const float* __restrict__ v_v,
              short* __restrict__ Qb, short* __restrict__ Kb,
              short* __restrict__ Vb) {
    __shared__ short A_lds[128][72];
    __shared__ short B_lds[64][72];
    const int t    = threadIdx.x;
    const int lane = t & 63;
    const int w    = t >> 6;
    const int c    = lane & 15;
    const int quad = lane >> 4;
    const int wm   = w >> 1;
    const int wn   = w & 1;
    const int m0 = blockIdx.x * 128;
    const int n0 = blockIdx.y * 64 + wn * 32;

    const int rowS = t >> 3;          // 0..31
    const int kc   = t & 7;
    const short* gA0 = Xt + (size_t)(m0 + rowS) * 256 + kc * 8;
    const short* gA1 = gA0 + 32 * 256;
    const short* gA2 = gA0 + 64 * 256;
    const short* gA3 = gA0 + 96 * 256;
    const short* gB0 = Wb + (size_t)(blockIdx.y * 64 + rowS) * 256 + kc * 8;
    const short* gB1 = gB0 + 32 * 256;
    short* lA0 = &A_lds[rowS][kc * 8];
    short* lA1 = &A_lds[rowS + 32][kc * 8];
    short* lA2 = &A_lds[rowS + 64][kc * 8];
    short* lA3 = &A_lds[rowS + 96][kc * 8];
    short* lB0 = &B_lds[rowS][kc * 8];
    short* lB1 = &B_lds[rowS + 32][kc * 8];

    f32x4 acc[4][2];
    #pragma unroll
    for (int f = 0; f < 4; ++f)
        #pragma unroll
        for (int g = 0; g < 2; ++g) acc[f][g] = (f32x4){0.f, 0.f, 0.f, 0.f};

    #pragma unroll
    for (int kt = 0; kt < 4; ++kt) {
        const int k0 = kt * 64;
        bf16x8 a0 = *(const bf16x8*)(gA0 + k0);
        bf16x8 a1 = *(const bf16x8*)(gA1 + k0);
        bf16x8 a2 = *(const bf16x8*)(gA2 + k0);
        bf16x8 a3 = *(const bf16x8*)(gA3 + k0);
        bf16x8 b0 = *(const bf16x8*)(gB0 + k0);
        bf16x8 b1 = *(const bf16x8*)(gB1 + k0);
        if (kt) __syncthreads();
        *(bf16x8*)lA0 = a0;
        *(bf16x8*)lA1 = a1;
        *(bf16x8*)lA2 = a2;
        *(bf16x8*)lA3 = a3;
        *(bf16x8*)lB0 = b0;
        *(bf16x8*)lB1 = b1;
        __syncthreads();
        #pragma unroll
        for (int s = 0; s < 2; ++s) {
            const int ko = s * 32 + quad * 8;
            bf16x8 af[4], bg[2];
            #pragma unroll
            for (int f = 0; f < 4; ++f)
                af[f] = *(const bf16x8*)&A_lds[wm * 64 + f * 16 + c][ko];
            #pragma unroll
            for (int g = 0; g < 2; ++g)
                bg[g] = *(const bf16x8*)&B_lds[wn * 32 + g * 16 + c][ko];
            #pragma unroll
            for (int f = 0; f < 4; ++f)
                #pragma unroll
                for (int g = 0; g < 2; ++g)
                    acc[f][g] = __builtin_amdgcn_mfma_f32_16x16x32_bf16(af[f], bg[g], acc[f][g], 0, 0, 0);
        }
    }

    const int mw = m0 + wm * 64;
    if (n0 < 512) {
        const bool isQ = (n0 < 256);
        short* dst = isQ ? Qb : Kb;
        const float fold = isQ ? ATT_SCALE : 1.0f;
        #pragma unroll
        for (int g = 0; g < 2; ++g) {
            const int o  = n0 + g * 16 + c;
            const int cd = o & 255;
            const int h  = cd >> 5;
            const int d  = cd & 31;
            float s    = g_qk[o] * rsqrtf(v_qk[o] + BN_EPS);
            float beta = (b_qk[o] - m_qk[o] * s) * fold;
            s *= fold;
            #pragma unroll
            for (int f = 0; f < 4; ++f) {
                #pragma unroll
                for (int r = 0; r < 4; ++r) {
                    const int row  = mw + f * 16 + (quad << 2) + r;   // global spatial
                    const int pair = (row >> 10) * NHD + h;
                    const int i    = row & 1023;
                    dst[(((size_t)pair << 10) + i) * HD + d] = f2bf(acc[f][g][r] * s + beta);
                }
            }
        }
    } else {
        #pragma unroll
        for (int g = 0; g < 2; ++g) {
            const int c2 = n0 + g * 16 + c - 512;   // v channel 0..255
            const int d  = c2 & 31;
            const int hp = c2 >> 5;
            const float s    = g_v[c2] * rsqrtf(v_v[c2] + BN_EPS);
            const float beta = b_v[c2] - m_v[c2] * s;
            #pragma unroll
            for (int f = 0; f < 4; ++f) {
                #pragma unroll
                for (int r = 0; r < 4; ++r) {
                    const int row  = mw + f * 16 + (quad << 2) + r;   // global spatial
                    const int pair = (row >> 10) * NHD + hp;
                    const int j    = row & 1023;
                    Vb[((size_t)pair << 15) + (d << 10) + j] = f2bf(acc[f][g][r] * s + beta);
                }
            }
        }
    }
}

// ---------------------------------------------------------------------------
// Kernel: MFMA flash attention v7 — R14 structure widened to 128 q-rows/block
// via 512-thread blocks (8 waves = 4 pidx x 2 jhalf). Same total wave count
// (4096 -> 4 waves/SIMD) but each staged 16 KB K/V tile now feeds 8 waves
// instead of 4: staging traffic and barrier-drains per CU HALVE, and each
// pair's K/V is read by 8 blocks instead of 16. Inner loop, no-max exp2
// softmax, additive merge (now 4 pidx groups) identical to R14.
// XCD swizzle: bx&7 = h. grid 512, block 512.
// ---------------------------------------------------------------------------
__global__ __launch_bounds__(512, 4)
void attn_kernel(const short* __restrict__ Qb,
                 const short* __restrict__ Kb,
                 const short* __restrict__ Vb,
                 short* __restrict__ AOt) {
    const int tid  = threadIdx.x;
    const int wave = tid >> 6;     // 0..7
    const int lane = tid & 63;
    const int c    = lane & 15;
    const int quad = lane >> 4;
    const int pidx  = wave >> 1;   // 0..3: which 32-row group of the 128 rows
    const int jhalf = wave & 1;    // which j-half

    // decode: h = bx&7 (XCD swizzle), ba = (bx>>3)&7, blk = bx>>6 (0..7)
    const int bx  = blockIdx.x;
    const int h   = bx & 7;
    const int ba  = (bx >> 3) & 7;
    const int blk = bx >> 6;                      // 128 q-rows per block
    const int p   = ba * NHD + h;
    const int i0a = (blk << 7) + (pidx << 5);
    const int i0b = i0a + 16;

    __shared__ __align__(16) short Klds[2][64][40];  // [jhalf][row][d], rows pre-permuted per 32-subtile
    __shared__ __align__(16) short Vlds[2][32][72];  // [jhalf][d][j within 64-tile]
    __shared__ f32x4 mrgA[4][4][64];   // [pidx][acc][lane]
    __shared__ float mrgL[4][2][64];   // [pidx][a/b][lane]

    const short* qbase = Qb + ((size_t)p << 15);
    const short* kbase = Kb + ((size_t)p << 15);
    const short* vbase = Vb + ((size_t)p << 15);

    // Q fragments: B[k=d=quad*8+t][n=i=c]  (pre-scaled by log2e/sqrt(32))
    bf16x8 qfa = *(const bf16x8*)(qbase + ((i0a + c) << 5) + (quad << 3));
    bf16x8 qfb = *(const bf16x8*)(qbase + ((i0b + c) << 5) + (quad << 3));

    // staging (2 chunks/thread: 1 K + 1 V). threads 0-255 -> jhalf 0, 256-511 -> jhalf 1
    const int sjh  = tid >> 8;
    const int srem = tid & 255;
    const int krow = srem >> 2;          // dest K row 0..63
    const int kkc  = srem & 3;           // 16B chunk (32 d = 4 chunks)
    const int jj_  = krow >> 5;
    const int r32  = krow & 31;
    const int r16  = r32 & 15;
    const int srcr = ((r16 >> 2) << 3) + (r16 & 3) + ((r32 >> 4) << 2) + (jj_ << 5);
    const short* kS = kbase + (((sjh << 9) + srcr) << 5) + kkc * 8;
    short* kD = &Klds[sjh][krow][kkc * 8];
    const int vrow = srem >> 3;          // d 0..31
    const int vkc  = srem & 7;           // 16B chunk (64 j = 8 chunks)
    const short* vS = vbase + (vrow << 10) + (sjh << 9) + vkc * 8;
    short* vD = &Vlds[sjh][vrow][vkc * 8];

    f32x4 acc0a = {0.f,0.f,0.f,0.f}, acc1a = {0.f,0.f,0.f,0.f};
    f32x4 acc0b = {0.f,0.f,0.f,0.f}, acc1b = {0.f,0.f,0.f,0.f};
    float la = 0.f, lb = 0.f;
    const f32x4 zero = {0.f,0.f,0.f,0.f};

    for (int it = 0; it < 8; ++it) {
        const int joff = it << 6;       // 0..448 within each j-half
        // stage loads issue first
        bf16x8 k0 = *(const bf16x8*)(kS + (joff << 5));
        bf16x8 v0 = *(const bf16x8*)(vS + joff);
        if (it) __syncthreads();          // prior iter's ds_reads complete
        *(bf16x8*)kD = k0;
        *(bf16x8*)vD = v0;
        __syncthreads();                  // tiles visible to all waves

        #pragma unroll
        for (int jj = 0; jj < 2; ++jj) {
            bf16x8 kf0 = *(const bf16x8*)&Klds[jhalf][(jj << 5) + c][quad << 3];
            bf16x8 kf1 = *(const bf16x8*)&Klds[jhalf][(jj << 5) + 16 + c][quad << 3];
            bf16x8 vf0 = *(const bf16x8*)&Vlds[jhalf][c][(jj << 5) + (quad << 3)];
            bf16x8 vf1 = *(const bf16x8*)&Vlds[jhalf][c + 16][(jj << 5) + (quad << 3)];

            f32x4 s0a = __builtin_amdgcn_mfma_f32_16x16x32_bf16(kf0, qfa, zero, 0, 0, 0);
            f32x4 s1a = __builtin_amdgcn_mfma_f32_16x16x32_bf16(kf1, qfa, zero, 0, 0, 0);
            f32x4 s0b = __builtin_amdgcn_mfma_f32_16x16x32_bf16(kf0, qfb, zero, 0, 0, 0);
            f32x4 s1b = __builtin_amdgcn_mfma_f32_16x16x32_bf16(kf1, qfb, zero, 0, 0, 0);

            float p0a[4], p1a[4], p0b[4], p1b[4];
            #pragma unroll
            for (int r = 0; r < 4; ++r) {
                p0a[r] = __builtin_amdgcn_exp2f(s0a[r]);
                p1a[r] = __builtin_amdgcn_exp2f(s1a[r]);
                p0b[r] = __builtin_amdgcn_exp2f(s0b[r]);
                p1b[r] = __builtin_amdgcn_exp2f(s1b[r]);
            }
            la += (p0a[0]+p0a[1]) + (p0a[2]+p0a[3]) + (p1a[0]+p1a[1]) + (p1a[2]+p1a[3]);
            lb += (p0b[0]+p0b[1]) + (p0b[2]+p0b[3]) + (p1b[0]+p1b[1]) + (p1b[2]+p1b[3]);

            union { unsigned int u[4]; bf16x8 v; } pfa, pfb;
            pfa.u[0] = pk2bf(p0a[0], p0a[1]);
            pfa.u[1] = pk2bf(p0a[2], p0a[3]);
            pfa.u[2] = pk2bf(p1a[0], p1a[1]);
            pfa.u[3] = pk2bf(p1a[2], p1a[3]);
            pfb.u[0] = pk2bf(p0b[0], p0b[1]);
            pfb.u[1] = pk2bf(p0b[2], p0b[3]);
            pfb.u[2] = pk2bf(p1b[0], p1b[1]);
            pfb.u[3] = pk2bf(p1b[2], p1b[3]);

            acc0a = __builtin_amdgcn_mfma_f32_16x16x32_bf16(pfa.v, vf0, acc0a, 0, 0, 0);
            acc1a = __builtin_amdgcn_mfma_f32_16x16x32_bf16(pfa.v, vf1, acc1a, 0, 0, 0);
            acc0b = __builtin_amdgcn_mfma_f32_16x16x32_bf16(pfb.v, vf0, acc0b, 0, 0, 0);
            acc1b = __builtin_amdgcn_mfma_f32_16x16x32_bf16(pfb.v, vf1, acc1b, 0, 0, 0);
        }
    }

    // merge the two j-halves per pidx group (partials are additive)
    __syncthreads();                      // last iter's ds_reads done
    if (jhalf == 1) {
        mrgA[pidx][0][lane] = acc0a;
        mrgA[pidx][1][lane] = acc1a;
        mrgA[pidx][2][lane] = acc0b;
        mrgA[pidx][3][lane] = acc1b;
        mrgL[pidx][0][lane] = la;
        mrgL[pidx][1][lane] = lb;
    }
    __syncthreads();
    if (jhalf == 1) return;

    acc0a += mrgA[pidx][0][lane];
    acc1a += mrgA[pidx][1][lane];
    acc0b += mrgA[pidx][2][lane];
    acc1b += mrgA[pidx][3][lane];
    la += mrgL[pidx][0][lane];
    lb += mrgL[pidx][1][lane];

    // l reduction across the 4 quads
    la += __shfl_xor(la, 16); la += __shfl_xor(la, 32);
    lb += __shfl_xor(lb, 16); lb += __shfl_xor(lb, 32);

    // Epilogue: AOt[(ba<<10)+i][h*32+d] bf16, coalesced 32B segments
    #pragma unroll
    for (int r = 0; r < 4; ++r) {
        const int rr = (quad << 2) + r;
        const float rla = 1.f / __shfl(la, rr, 16);
        const float rlb = 1.f / __shfl(lb, rr, 16);
        const size_t basea = ((((size_t)ba << 10) + i0a + rr) << 8) + (h << 5);
        const size_t baseb = ((((size_t)ba << 10) + i0b + rr) << 8) + (h << 5);
        AOt[basea + c]      = f2bf(acc0a[r] * rla);
        AOt[basea + c + 16] = f2bf(acc1a[r] * rla);
        AOt[baseb + c]      = f2bf(acc0b[r] * rlb);
        AOt[baseb + c + 16] = f2bf(acc1b[r] * rlb);
    }
}

// ---------------------------------------------------------------------------
// Kernel: P GEMM, LDS-STAGED (proven, untouched).
// D[o][n] = sum_c Wp[o][c] * AOt[n][c]. Block tile 64x64xBK=64, grid (4, 128).
// Epilogue BN -> f32 out, coalesced.
// ---------------------------------------------------------------------------
__global__ __launch_bounds__(256)
void pconv_gemm(const short* __restrict__ Wp, const short* __restrict__ AOt,
                const float* __restrict__ g_p, const float* __restrict__ b_p,
                const float* __restrict__ m_p, const float* __restrict__ v_p,
                float* __restrict__ out) {
    __shared__ short A_lds[64][72];
    __shared__ short B_lds[64][72];
    const int t    = threadIdx.x;
    const int lane = t & 63;
    const int w    = t >> 6;
    const int c    = lane & 15;
    const int quad = lane >> 4;
    const int wm   = w >> 1;
    const int wn   = w & 1;
    const int m0 = blockIdx.x * 64;
    const int n0 = blockIdx.y * 64;

    const int rowS = t >> 3;
    const int kc   = t & 7;
    const short* gA0 = Wp + (size_t)(m0 + rowS) * 256 + kc * 8;
    const short* gA1 = gA0 + 32 * 256;
    const short* gB0 = AOt + (size_t)(n0 + rowS) * 256 + kc * 8;
    const short* gB1 = gB0 + 32 * 256;
    short* lA0 = &A_lds[rowS][kc * 8];
    short* lA1 = &A_lds[rowS + 32][kc * 8];
    short* lB0 = &B_lds[rowS][kc * 8];
    short* lB1 = &B_lds[rowS + 32][kc * 8];

    f32x4 acc[2][2];
    #pragma unroll
    for (int f = 0; f < 2; ++f)
        #pragma unroll
        for (int g = 0; g < 2; ++g) acc[f][g] = (f32x4){0.f, 0.f, 0.f, 0.f};

    #pragma unroll
    for (int kt = 0; kt < 4; ++kt) {
        const int k0 = kt * 64;
        bf16x8 a0 = *(const bf16x8*)(gA0 + k0);
        bf16x8 a1 = *(const bf16x8*)(gA1 + k0);
        bf16x8 b0 = *(const bf16x8*)(gB0 + k0);
        bf16x8 b1 = *(const bf16x8*)(gB1 + k0);
        if (kt) __syncthreads();
        *(bf16x8*)lA0 = a0;
        *(bf16x8*)lA1 = a1;
        *(bf16x8*)lB0 = b0;
        *(bf16x8*)lB1 = b1;
        __syncthreads();
        #pragma unroll
        for (int s = 0; s < 2; ++s) {
            const int ko = s * 32 + quad * 8;
            bf16x8 af0 = *(const bf16x8*)&A_lds[wm * 32 + c][ko];
            bf16x8 af1 = *(const bf16x8*)&A_lds[wm * 32 + 16 + c][ko];
            bf16x8 bg0 = *(const bf16x8*)&B_lds[wn * 32 + c][ko];
            bf16x8 bg1 = *(const bf16x8*)&B_lds[wn * 32 + 16 + c][ko];
            acc[0][0] = __builtin_amdgcn_mfma_f32_16x16x32_bf16(af0, bg0, acc[0][0], 0, 0, 0);
            acc[0][1] = __builtin_amdgcn_mfma_f32_16x16x32_bf16(af0, bg1, acc[0][1], 0, 0, 0);
            acc[1][0] = __builtin_amdgcn_mfma_f32_16x16x32_bf16(af1, bg0, acc[1][0], 0, 0, 0);
            acc[1][1] = __builtin_amdgcn_mfma_f32_16x16x32_bf16(af1, bg1, acc[1][1], 0, 0, 0);
        }
    }

    const int mw = m0 + wm * 32;
    const int nw = n0 + wn * 32;
    #pragma unroll
    for (int f = 0; f < 2; ++f) {
        #pragma unroll
        for (int r = 0; r < 4; ++r) {
            const int o = mw + f * 16 + (quad << 2) + r;
            const float s    = g_p[o] * rsqrtf(v_p[o] + BN_EPS);
            const float beta = b_p[o] - m_p[o] * s;
            #pragma unroll
            for (int g = 0; g < 2; ++g) {
                const int col = nw + g * 16 + c;           // global spatial
                const int b = col >> 12, n = col & 4095;
                out[((size_t)(b * CCH + o) << 12) + n] = acc[f][g][r] * s + beta;
            }
        }
    }
}

// ---------------------------------------------------------------------------
extern "C" void kernel_launch(void* const* d_in, const int* in_sizes, int n_in,
                              void* d_out, int out_size, void* d_ws, size_t ws_size,
                              hipStream_t stream) {
    const float* x    = (const float*)d_in[0];
    const float* w_qk = (const float*)d_in[1];
    const float* g_qk = (const float*)d_in[2];
    const float* b_qk = (const float*)d_in[3];
    const float* m_qk = (const float*)d_in[4];
    const float* v_qk = (const float*)d_in[5];
    const float* w_v  = (const float*)d_in[6];
    const float* g_v  = (const float*)d_in[7];
    const float* b_v  = (const float*)d_in[8];
    const float* m_v  = (const float*)d_in[9];
    const float* v_v  = (const float*)d_in[10];
    const float* w_p  = (const float*)d_in[11];
    const float* g_p  = (const float*)d_in[12];
    const float* b_p  = (const float*)d_in[13];
    const float* m_p  = (const float*)d_in[14];
    const float* v_p  = (const float*)d_in[15];

    // ws layout (shorts): Qb | Kb | Vb | Xt | Wb ; AOt aliases Xt (dead by attn)
    short* Qb  = (short*)d_ws;
    short* Kb  = Qb + 2097152;
    short* Vb  = Kb + 2097152;
    short* Xt  = Vb + 2097152;
    short* Wb  = Xt + 2097152;
    short* AOt = Xt;

    dim3 gprep(64, 4, 3);
    prep_kernel<<<gprep, 256, 0, stream>>>(x, Xt, w_qk, w_v, w_p, Wb);

    dim3 gqkv(64, 12);
    qkv_gemm<<<gqkv, 256, 0, stream>>>(Xt, Wb, g_qk, b_qk, m_qk, v_qk,
                                       g_v, b_v, m_v, v_v, Qb, Kb, Vb);

    attn_kernel<<<512, 512, 0, stream>>>(Qb, Kb, Vb, AOt);

    dim3 gp(4, 128);
    pconv_gemm<<<gp, 256, 0, stream>>>(Wb + 768 * 256, AOt, g_p, b_p, m_p, v_p, (float*)d_out);
}

// Round 16
// 122.584 us; speedup vs baseline: 1.0229x; 1.0229x over previous
//
#include <hip/hip_runtime.h>
#include <hip/hip_bf16.h>
#include <math.h>

// Problem constants (B=2, C=256, H=W=64, NUM_HEADS=8, AREA=4)
#define CCH   256
#define NPIX  4096
#define NHD   8
#define HD    32
#define NA    1024
#define BN_EPS 1e-5f
// 1/sqrt(32) * log2(e): folded into Q at qkv_gemm so attn uses raw exp2
#define ATT_SCALE (0.17677669529663687f * 1.4426950408889634f)

typedef __attribute__((ext_vector_type(8))) short bf16x8;
typedef __attribute__((ext_vector_type(4))) short bf16x4;
typedef __attribute__((ext_vector_type(4))) float f32x4;

static __device__ inline short f2bf(float f) {
    union { float f; unsigned u; } v; v.f = f;
    unsigned r = (v.u + 0x7fff + ((v.u >> 16) & 1)) >> 16;  // RNE
    return (short)r;
}

// packed RNE f32x2 -> bf16x2 (low = a, high = b)
static __device__ inline unsigned int pk2bf(float a, float b) {
    __hip_bfloat162 h2 = __float22bfloat162_rn(make_float2(a, b));
    union { __hip_bfloat162 h; unsigned int u; } v; v.h = h2;
    return v.u;
}

// ---------------------------------------------------------------------------
// Kernel: fused input prep (proven, untouched).
//  z = 0,1 : transpose+cast x[b][c][n] f32 -> Xt[b*4096+n][c] bf16 (b = z).
//  z = 2   : cast all weights to bf16 into Wb.
// grid (64, 4, 3), block 256.
// ---------------------------------------------------------------------------
__global__ __launch_bounds__(256)
void prep_kernel(const float* __restrict__ x, short* __restrict__ Xt,
                 const float* __restrict__ wqk, const float* __restrict__ wv,
                 const float* __restrict__ wp, short* __restrict__ Wb) {
    __shared__ short tile[64][66];
    const int t = threadIdx.x;
    const int z = blockIdx.z;
    if (z == 2) {
        const int id  = blockIdx.y * 64 + blockIdx.x;        // 0..255
        const int idx = (id * 256 + t) * 4;
        const float* src; int off;
        if (idx < 131072)      { src = wqk; off = idx; }
        else if (idx < 196608) { src = wv;  off = idx - 131072; }
        else                   { src = wp;  off = idx - 196608; }
        const float4 v = *(const float4*)(src + off);
        short4 o;
        o.x = f2bf(v.x); o.y = f2bf(v.y); o.z = f2bf(v.z); o.w = f2bf(v.w);
        *(short4*)(Wb + idx) = o;
        return;
    }
    const int n0 = blockIdx.x << 6;
    const int c0 = blockIdx.y << 6;
    const int b  = z;
    const float* xp = x + (((size_t)(b * CCH + c0)) << 12) + n0;
    #pragma unroll
    for (int j = 0; j < 16; ++j) {
        const int lin = (j << 8) + t;
        const int cl = lin >> 6, nl = lin & 63;
        tile[cl][nl] = f2bf(xp[((size_t)cl << 12) + nl]);
    }
    __syncthreads();
    short* xtp = Xt + ((((size_t)b << 12) + n0) << 8) + c0;
    #pragma unroll
    for (int j = 0; j < 16; ++j) {
        const int lin = (j << 8) + t;
        const int nl = lin >> 6, cl = lin & 63;
        xtp[((size_t)nl << 8) + cl] = tile[cl][nl];
    }
}

// ---------------------------------------------------------------------------
// Kernel: fused QKV GEMM, LDS-staged, 128x64 block tile (R14 proven, untouched).
// D[i][o] = sum_c Xt[i][c] * Wb[o][c], i=0..8191, o=0..767.
// Block tile 128m x 64n x BK=64; 4 waves (2m x 2n), wave tile 64x32.
// grid (64, 12) = 768 blocks, 3 blocks/CU.
// ---------------------------------------------------------------------------
__global__ __launch_bounds__(256)
void qkv_gemm(const short* __restrict__ Xt, const short* __restrict__ Wb,
              const float* __restrict__ g_qk, const float* __restrict__ b_qk,
              const float* __restrict__ m_qk, const float* __restrict__ v_qk,
              const float* __restrict__ g_v, const float* __restrict__ b_v,
              const float* __restrict__ m_v, const float* __restrict__ v_v,
              short* __restrict__ Qb, short* __restrict__ Kb,
              short* __restrict__ Vb) {
    __shared__ short A_lds[128][72];
    __shared__ short B_lds[64][72];
    const int t    = threadIdx.x;
    const int lane = t & 63;
    const int w    = t >> 6;
    const int c    = lane & 15;
    const int quad = lane >> 4;
    const int wm   = w >> 1;
    const int wn   = w & 1;
    const int m0 = blockIdx.x * 128;
    const int n0 = blockIdx.y * 64 + wn * 32;

    const int rowS = t >> 3;          // 0..31
    const int kc   = t & 7;
    const short* gA0 = Xt + (size_t)(m0 + rowS) * 256 + kc * 8;
    const short* gA1 = gA0 + 32 * 256;
    const short* gA2 = gA0 + 64 * 256;
    const short* gA3 = gA0 + 96 * 256;
    const short* gB0 = Wb + (size_t)(blockIdx.y * 64 + rowS) * 256 + kc * 8;
    const short* gB1 = gB0 + 32 * 256;
    short* lA0 = &A_lds[rowS][kc * 8];
    short* lA1 = &A_lds[rowS + 32][kc * 8];
    short* lA2 = &A_lds[rowS + 64][kc * 8];
    short* lA3 = &A_lds[rowS + 96][kc * 8];
    short* lB0 = &B_lds[rowS][kc * 8];
    short* lB1 = &B_lds[rowS + 32][kc * 8];

    f32x4 acc[4][2];
    #pragma unroll
    for (int f = 0; f < 4; ++f)
        #pragma unroll
        for (int g = 0; g < 2; ++g) acc[f][g] = (f32x4){0.f, 0.f, 0.f, 0.f};

    #pragma unroll
    for (int kt = 0; kt < 4; ++kt) {
        const int k0 = kt * 64;
        bf16x8 a0 = *(const bf16x8*)(gA0 + k0);
        bf16x8 a1 = *(const bf16x8*)(gA1 + k0);
        bf16x8 a2 = *(const bf16x8*)(gA2 + k0);
        bf16x8 a3 = *(const bf16x8*)(gA3 + k0);
        bf16x8 b0 = *(const bf16x8*)(gB0 + k0);
        bf16x8 b1 = *(const bf16x8*)(gB1 + k0);
        if (kt) __syncthreads();
        *(bf16x8*)lA0 = a0;
        *(bf16x8*)lA1 = a1;
        *(bf16x8*)lA2 = a2;
        *(bf16x8*)lA3 = a3;
        *(bf16x8*)lB0 = b0;
        *(bf16x8*)lB1 = b1;
        __syncthreads();
        #pragma unroll
        for (int s = 0; s < 2; ++s) {
            const int ko = s * 32 + quad * 8;
            bf16x8 af[4], bg[2];
            #pragma unroll
            for (int f = 0; f < 4; ++f)
                af[f] = *(const bf16x8*)&A_lds[wm * 64 + f * 16 + c][ko];
            #pragma unroll
            for (int g = 0; g < 2; ++g)
                bg[g] = *(const bf16x8*)&B_lds[wn * 32 + g * 16 + c][ko];
            #pragma unroll
            for (int f = 0; f < 4; ++f)
                #pragma unroll
                for (int g = 0; g < 2; ++g)
                    acc[f][g] = __builtin_amdgcn_mfma_f32_16x16x32_bf16(af[f], bg[g], acc[f][g], 0, 0, 0);
        }
    }

    const int mw = m0 + wm * 64;
    if (n0 < 512) {
        const bool isQ = (n0 < 256);
        short* dst = isQ ? Qb : Kb;
        const float fold = isQ ? ATT_SCALE : 1.0f;
        #pragma unroll
        for (int g = 0; g < 2; ++g) {
            const int o  = n0 + g * 16 + c;
            const int cd = o & 255;
            const int h  = cd >> 5;
            const int d  = cd & 31;
            float s    = g_qk[o] * rsqrtf(v_qk[o] + BN_EPS);
            float beta = (b_qk[o] - m_qk[o] * s) * fold;
            s *= fold;
            #pragma unroll
            for (int f = 0; f < 4; ++f) {
                #pragma unroll
                for (int r = 0; r < 4; ++r) {
                    const int row  = mw + f * 16 + (quad << 2) + r;   // global spatial
                    const int pair = (row >> 10) * NHD + h;
                    const int i    = row & 1023;
                    dst[(((size_t)pair << 10) + i) * HD + d] = f2bf(acc[f][g][r] * s + beta);
                }
            }
        }
    } else {
        #pragma unroll
        for (int g = 0; g < 2; ++g) {
            const int c2 = n0 + g * 16 + c - 512;   // v channel 0..255
            const int d  = c2 & 31;
            const int hp = c2 >> 5;
            const float s    = g_v[c2] * rsqrtf(v_v[c2] + BN_EPS);
            const float beta = b_v[c2] - m_v[c2] * s;
            #pragma unroll
            for (int f = 0; f < 4; ++f) {
                #pragma unroll
                for (int r = 0; r < 4; ++r) {
                    const int row  = mw + f * 16 + (quad << 2) + r;   // global spatial
                    const int pair = (row >> 10) * NHD + hp;
                    const int j    = row & 1023;
                    Vb[((size_t)pair << 15) + (d << 10) + j] = f2bf(acc[f][g][r] * s + beta);
                }
            }
        }
    }
}

// ---------------------------------------------------------------------------
// Kernel: MFMA flash attention v6 (R14 proven config, reverted from R15's
// 512-thread experiment). BJ=64 staging (2 j-subtiles per stage), j-split x2,
// K rows PRE-PERMUTED per 32-row subtile, no-max exp2 softmax, additive
// 2-way merge. XCD swizzle: bx&7 = h. grid 1024, block 256.
// ---------------------------------------------------------------------------
__global__ __launch_bounds__(256, 4)
void attn_kernel(const short* __restrict__ Qb,
                 const short* __restrict__ Kb,
                 const short* __restrict__ Vb,
                 short* __restrict__ AOt) {
    const int tid  = threadIdx.x;
    const int wave = tid >> 6;
    const int lane = tid & 63;
    const int c    = lane & 15;
    const int quad = lane >> 4;
    const int pidx  = wave >> 1;   // which 32-row group of the block's 64 rows
    const int jhalf = wave & 1;    // which j-half

    // swizzled decode: bx = (p&7) + 8*(16*(p>>3) + blk)
    const int bx  = blockIdx.x;
    const int hi  = bx >> 3;                      // 0..127
    const int p   = (bx & 7) + ((hi >> 4) << 3);  // pair 0..63
    const int blk = hi & 15;                      // 64 q-rows per block
    const int i0a = (blk << 6) + (pidx << 5);
    const int i0b = i0a + 16;
    const int ba  = p >> 3;
    const int h   = p & 7;

    __shared__ __align__(16) short Klds[2][64][40];  // [jhalf][row][d], rows pre-permuted per 32-subtile
    __shared__ __align__(16) short Vlds[2][32][72];  // [jhalf][d][j within 64-tile]
    __shared__ f32x4 mrgA[2][4][64];   // [pidx][acc][lane]
    __shared__ float mrgL[2][2][64];   // [pidx][a/b][lane]

    const short* qbase = Qb + ((size_t)p << 15);
    const short* kbase = Kb + ((size_t)p << 15);
    const short* vbase = Vb + ((size_t)p << 15);

    // Q fragments: B[k=d=quad*8+t][n=i=c]  (pre-scaled by log2e/sqrt(32))
    bf16x8 qfa = *(const bf16x8*)(qbase + ((i0a + c) << 5) + (quad << 3));
    bf16x8 qfb = *(const bf16x8*)(qbase + ((i0b + c) << 5) + (quad << 3));

    // staging (4 chunks/thread: K both jhalves + V both jhalves)
    const int krow = tid >> 2;          // dest K row 0..63
    const int kkc  = tid & 3;           // 16B chunk (32 d = 4 chunks)
    const int jj_  = krow >> 5;
    const int r32  = krow & 31;
    const int r16  = r32 & 15;
    const int srcr = ((r16 >> 2) << 3) + (r16 & 3) + ((r32 >> 4) << 2) + (jj_ << 5);
    const short* kS = kbase + (srcr << 5) + kkc * 8;
    short* kD0 = &Klds[0][krow][kkc * 8];
    short* kD1 = &Klds[1][krow][kkc * 8];
    const int vrow = tid >> 3;          // d 0..31
    const int vkc  = tid & 7;           // 16B chunk (64 j = 8 chunks)
    const short* vS = vbase + (vrow << 10) + vkc * 8;
    short* vD0 = &Vlds[0][vrow][vkc * 8];
    short* vD1 = &Vlds[1][vrow][vkc * 8];

    f32x4 acc0a = {0.f,0.f,0.f,0.f}, acc1a = {0.f,0.f,0.f,0.f};
    f32x4 acc0b = {0.f,0.f,0.f,0.f}, acc1b = {0.f,0.f,0.f,0.f};
    float la = 0.f, lb = 0.f;
    const f32x4 zero = {0.f,0.f,0.f,0.f};

    for (int it = 0; it < 8; ++it) {
        const int joff = it << 6;       // 0..448 within each j-half
        // stage loads issue first (overlap prior iteration's compute drain)
        bf16x8 k0 = *(const bf16x8*)(kS + (joff << 5));
        bf16x8 k1 = *(const bf16x8*)(kS + ((joff + 512) << 5));
        bf16x8 v0 = *(const bf16x8*)(vS + joff);
        bf16x8 v1 = *(const bf16x8*)(vS + joff + 512);
        if (it) __syncthreads();          // prior iter's ds_reads complete
        *(bf16x8*)kD0 = k0;
        *(bf16x8*)kD1 = k1;
        *(bf16x8*)vD0 = v0;
        *(bf16x8*)vD1 = v1;
        __syncthreads();                  // tiles visible to all waves

        #pragma unroll
        for (int jj = 0; jj < 2; ++jj) {
            bf16x8 kf0 = *(const bf16x8*)&Klds[jhalf][(jj << 5) + c][quad << 3];
            bf16x8 kf1 = *(const bf16x8*)&Klds[jhalf][(jj << 5) + 16 + c][quad << 3];
            bf16x8 vf0 = *(const bf16x8*)&Vlds[jhalf][c][(jj << 5) + (quad << 3)];
            bf16x8 vf1 = *(const bf16x8*)&Vlds[jhalf][c + 16][(jj << 5) + (quad << 3)];

            f32x4 s0a = __builtin_amdgcn_mfma_f32_16x16x32_bf16(kf0, qfa, zero, 0, 0, 0);
            f32x4 s1a = __builtin_amdgcn_mfma_f32_16x16x32_bf16(kf1, qfa, zero, 0, 0, 0);
            f32x4 s0b = __builtin_amdgcn_mfma_f32_16x16x32_bf16(kf0, qfb, zero, 0, 0, 0);
            f32x4 s1b = __builtin_amdgcn_mfma_f32_16x16x32_bf16(kf1, qfb, zero, 0, 0, 0);

            float p0a[4], p1a[4], p0b[4], p1b[4];
            #pragma unroll
            for (int r = 0; r < 4; ++r) {
                p0a[r] = __builtin_amdgcn_exp2f(s0a[r]);
                p1a[r] = __builtin_amdgcn_exp2f(s1a[r]);
                p0b[r] = __builtin_amdgcn_exp2f(s0b[r]);
                p1b[r] = __builtin_amdgcn_exp2f(s1b[r]);
            }
            la += (p0a[0]+p0a[1]) + (p0a[2]+p0a[3]) + (p1a[0]+p1a[1]) + (p1a[2]+p1a[3]);
            lb += (p0b[0]+p0b[1]) + (p0b[2]+p0b[3]) + (p1b[0]+p1b[1]) + (p1b[2]+p1b[3]);

            union { unsigned int u[4]; bf16x8 v; } pfa, pfb;
            pfa.u[0] = pk2bf(p0a[0], p0a[1]);
            pfa.u[1] = pk2bf(p0a[2], p0a[3]);
            pfa.u[2] = pk2bf(p1a[0], p1a[1]);
            pfa.u[3] = pk2bf(p1a[2], p1a[3]);
            pfb.u[0] = pk2bf(p0b[0], p0b[1]);
            pfb.u[1] = pk2bf(p0b[2], p0b[3]);
            pfb.u[2] = pk2bf(p1b[0], p1b[1]);
            pfb.u[3] = pk2bf(p1b[2], p1b[3]);

            acc0a = __builtin_amdgcn_mfma_f32_16x16x32_bf16(pfa.v, vf0, acc0a, 0, 0, 0);
            acc1a = __builtin_amdgcn_mfma_f32_16x16x32_bf16(pfa.v, vf1, acc1a, 0, 0, 0);
            acc0b = __builtin_amdgcn_mfma_f32_16x16x32_bf16(pfb.v, vf0, acc0b, 0, 0, 0);
            acc1b = __builtin_amdgcn_mfma_f32_16x16x32_bf16(pfb.v, vf1, acc1b, 0, 0, 0);
        }
    }

    // merge the two j-halves (partials are additive: no-max softmax)
    __syncthreads();                      // last iter's ds_reads done
    if (jhalf == 1) {
        mrgA[pidx][0][lane] = acc0a;
        mrgA[pidx][1][lane] = acc1a;
        mrgA[pidx][2][lane] = acc0b;
        mrgA[pidx][3][lane] = acc1b;
        mrgL[pidx][0][lane] = la;
        mrgL[pidx][1][lane] = lb;
    }
    __syncthreads();
    if (jhalf == 1) return;

    acc0a += mrgA[pidx][0][lane];
    acc1a += mrgA[pidx][1][lane];
    acc0b += mrgA[pidx][2][lane];
    acc1b += mrgA[pidx][3][lane];
    la += mrgL[pidx][0][lane];
    lb += mrgL[pidx][1][lane];

    // l reduction across the 4 quads
    la += __shfl_xor(la, 16); la += __shfl_xor(la, 32);
    lb += __shfl_xor(lb, 16); lb += __shfl_xor(lb, 32);

    // Epilogue: AOt[(ba<<10)+i][h*32+d] bf16, coalesced 32B segments
    #pragma unroll
    for (int r = 0; r < 4; ++r) {
        const int rr = (quad << 2) + r;
        const float rla = 1.f / __shfl(la, rr, 16);
        const float rlb = 1.f / __shfl(lb, rr, 16);
        const size_t basea = ((((size_t)ba << 10) + i0a + rr) << 8) + (h << 5);
        const size_t baseb = ((((size_t)ba << 10) + i0b + rr) << 8) + (h << 5);
        AOt[basea + c]      = f2bf(acc0a[r] * rla);
        AOt[basea + c + 16] = f2bf(acc1a[r] * rla);
        AOt[baseb + c]      = f2bf(acc0b[r] * rlb);
        AOt[baseb + c + 16] = f2bf(acc1b[r] * rlb);
    }
}

// ---------------------------------------------------------------------------
// Kernel: P GEMM, LDS-staged, WIDENED to 64m x 128n (qkv-proven widening on
// the N side): 16 MFMA : 12 ds_read per k-tile, 33% fewer staged bytes/FLOP.
// D[o][n] = sum_c Wp[o][c] * AOt[n][c]. 4 waves (2m x 2n), wave tile 32x64.
// grid (4, 64) = 256 blocks. Epilogue BN -> f32 out, coalesced.
// ---------------------------------------------------------------------------
__global__ __launch_bounds__(256)
void pconv_gemm(const short* __restrict__ Wp, const short* __restrict__ AOt,
                const float* __restrict__ g_p, const float* __restrict__ b_p,
                const float* __restrict__ m_p, const float* __restrict__ v_p,
                float* __restrict__ out) {
    __shared__ short A_lds[64][72];
    __shared__ short B_lds[128][72];
    const int t    = threadIdx.x;
    const int lane = t & 63;
    const int w    = t >> 6;
    const int c    = lane & 15;
    const int quad = lane >> 4;
    const int wm   = w >> 1;
    const int wn   = w & 1;
    const int m0 = blockIdx.x * 64;
    const int n0 = blockIdx.y * 128 + wn * 64;

    const int rowS = t >> 3;          // 0..31
    const int kc   = t & 7;
    const short* gA0 = Wp + (size_t)(m0 + rowS) * 256 + kc * 8;
    const short* gA1 = gA0 + 32 * 256;
    const short* gB0 = AOt + (size_t)(blockIdx.y * 128 + rowS) * 256 + kc * 8;
    const short* gB1 = gB0 + 32 * 256;
    const short* gB2 = gB0 + 64 * 256;
    const short* gB3 = gB0 + 96 * 256;
    short* lA0 = &A_lds[rowS][kc * 8];
    short* lA1 = &A_lds[rowS + 32][kc * 8];
    short* lB0 = &B_lds[rowS][kc * 8];
    short* lB1 = &B_lds[rowS + 32][kc * 8];
    short* lB2 = &B_lds[rowS + 64][kc * 8];
    short* lB3 = &B_lds[rowS + 96][kc * 8];

    f32x4 acc[2][4];
    #pragma unroll
    for (int f = 0; f < 2; ++f)
        #pragma unroll
        for (int g = 0; g < 4; ++g) acc[f][g] = (f32x4){0.f, 0.f, 0.f, 0.f};

    #pragma unroll
    for (int kt = 0; kt < 4; ++kt) {
        const int k0 = kt * 64;
        bf16x8 a0 = *(const bf16x8*)(gA0 + k0);
        bf16x8 a1 = *(const bf16x8*)(gA1 + k0);
        bf16x8 b0 = *(const bf16x8*)(gB0 + k0);
        bf16x8 b1 = *(const bf16x8*)(gB1 + k0);
        bf16x8 b2 = *(const bf16x8*)(gB2 + k0);
        bf16x8 b3 = *(const bf16x8*)(gB3 + k0);
        if (kt) __syncthreads();
        *(bf16x8*)lA0 = a0;
        *(bf16x8*)lA1 = a1;
        *(bf16x8*)lB0 = b0;
        *(bf16x8*)lB1 = b1;
        *(bf16x8*)lB2 = b2;
        *(bf16x8*)lB3 = b3;
        __syncthreads();
        #pragma unroll
        for (int s = 0; s < 2; ++s) {
            const int ko = s * 32 + quad * 8;
            bf16x8 af[2], bg[4];
            #pragma unroll
            for (int f = 0; f < 2; ++f)
                af[f] = *(const bf16x8*)&A_lds[wm * 32 + f * 16 + c][ko];
            #pragma unroll
            for (int g = 0; g < 4; ++g)
                bg[g] = *(const bf16x8*)&B_lds[wn * 64 + g * 16 + c][ko];
            #pragma unroll
            for (int f = 0; f < 2; ++f)
                #pragma unroll
                for (int g = 0; g < 4; ++g)
                    acc[f][g] = __builtin_amdgcn_mfma_f32_16x16x32_bf16(af[f], bg[g], acc[f][g], 0, 0, 0);
        }
    }

    const int mw = m0 + wm * 32;
    #pragma unroll
    for (int f = 0; f < 2; ++f) {
        #pragma unroll
        for (int r = 0; r < 4; ++r) {
            const int o = mw + f * 16 + (quad << 2) + r;
            const float s    = g_p[o] * rsqrtf(v_p[o] + BN_EPS);
            const float beta = b_p[o] - m_p[o] * s;
            #pragma unroll
            for (int g = 0; g < 4; ++g) {
                const int col = n0 + g * 16 + c;           // global spatial
                const int b = col >> 12, n = col & 4095;
                out[((size_t)(b * CCH + o) << 12) + n] = acc[f][g][r] * s + beta;
            }
        }
    }
}

// ---------------------------------------------------------------------------
extern "C" void kernel_launch(void* const* d_in, const int* in_sizes, int n_in,
                              void* d_out, int out_size, void* d_ws, size_t ws_size,
                              hipStream_t stream) {
    const float* x    = (const float*)d_in[0];
    const float* w_qk = (const float*)d_in[1];
    const float* g_qk = (const float*)d_in[2];
    const float* b_qk = (const float*)d_in[3];
    const float* m_qk = (const float*)d_in[4];
    const float* v_qk = (const float*)d_in[5];
    const float* w_v  = (const float*)d_in[6];
    const float* g_v  = (const float*)d_in[7];
    const float* b_v  = (const float*)d_in[8];
    const float* m_v  = (const float*)d_in[9];
    const float* v_v  = (const float*)d_in[10];
    const float* w_p  = (const float*)d_in[11];
    const float* g_p  = (const float*)d_in[12];
    const float* b_p  = (const float*)d_in[13];
    const float* m_p  = (const float*)d_in[14];
    const float* v_p  = (const float*)d_in[15];

    // ws layout (shorts): Qb | Kb | Vb | Xt | Wb ; AOt aliases Xt (dead by attn)
    short* Qb  = (short*)d_ws;
    short* Kb  = Qb + 2097152;
    short* Vb  = Kb + 2097152;
    short* Xt  = Vb + 2097152;
    short* Wb  = Xt + 2097152;
    short* AOt = Xt;

    dim3 gprep(64, 4, 3);
    prep_kernel<<<gprep, 256, 0, stream>>>(x, Xt, w_qk, w_v, w_p, Wb);

    dim3 gqkv(64, 12);
    qkv_gemm<<<gqkv, 256, 0, stream>>>(Xt, Wb, g_qk, b_qk, m_qk, v_qk,
                                       g_v, b_v, m_v, v_v, Qb, Kb, Vb);

    attn_kernel<<<1024, 256, 0, stream>>>(Qb, Kb, Vb, AOt);

    dim3 gp(4, 64);
    pconv_gemm<<<gp, 256, 0, stream>>>(Wb + 768 * 256, AOt, g_p, b_p, m_p, v_p, (float*)d_out);
}